// Round 4
// baseline (9148.956 us; speedup 1.0000x reference)
//
#include <hip/hip_runtime.h>
#include <hip/hip_bf16.h>

#define HID 4096
#define NEMBD 64
#define NBATCH 32
#define NTIME 64
#define NVOCAB 256
#define G4 16384

typedef __attribute__((ext_vector_type(4))) float f32x4;
typedef __attribute__((ext_vector_type(8))) short s16x8;

__device__ __forceinline__ unsigned short f2bf(float f) {
  union { float f; unsigned u; } v; v.f = f;
  unsigned u = v.u + 0x7FFFu + ((v.u >> 16) & 1u);
  return (unsigned short)(u >> 16);
}

__device__ __forceinline__ unsigned long long pk2f(float a, float b) {
  union { float f[2]; unsigned long long u; } v; v.f[0] = a; v.f[1] = b; return v.u;
}

// A-fragment packed offset for a [32 rows][4096 k] bf16 matrix, chunked by 32k:
// chunk*1024 + tile512*(row>=16) + lane*8 + elem, lane = (row&15) | (((k>>3)&3)<<4)
__device__ __forceinline__ int apoff(int b, int j) {
  return ((j >> 5) << 10) | ((b >> 4) << 9) |
         (((b & 15) | (((j >> 3) & 3) << 4)) << 3) | (j & 7);
}

// ---------------- stage 1: partial column sums of squares (deterministic K-split) ----
__global__ void colsum_k(const float* __restrict__ w, float* __restrict__ ss,
                         int K, int N, int KS) {
  int col = threadIdx.x & 63, kg = threadIdx.x >> 6;
  int j = blockIdx.x * 64 + col;
  int kper = K / KS;
  int k0 = blockIdx.y * kper;
  float s = 0.f;
#pragma unroll 4
  for (int k = k0 + kg; k < k0 + kper; k += 4) {
    float v = w[(size_t)k * N + j];
    s += v * v;
  }
  __shared__ float red[4][64];
  red[kg][col] = s;
  __syncthreads();
  if (threadIdx.x < 64)
    ss[(size_t)blockIdx.y * N + j] = red[0][col] + red[1][col] + red[2][col] + red[3][col];
}

// ---------------- pack fp32 [K][N] column-slice into bf16 B-fragment order -----------
__global__ void pack_k(const float* __restrict__ src, const float* __restrict__ ss,
                       const float* __restrict__ g, unsigned short* __restrict__ dst,
                       int N, int Cw, int S, int Kw, int nch, int KS) {
  int bid = blockIdx.x;
  int colbase = (bid & 3) * Cw + (bid >> S) * 16;
  int kbase = (bid & 3) * Kw;
  int cper = nch / gridDim.y;
  int c0 = blockIdx.y * cper;
  size_t dstbase = (size_t)bid * nch * 512 + (size_t)c0 * 512;
  __shared__ unsigned short tile[512];
  int tid = threadIdx.x;
  int col16 = tid & 15, kk = tid >> 4;
  float sc = 1.f;
  if (ss) {
    float t = 0.f;
    for (int q = 0; q < KS; ++q) t += ss[(size_t)q * N + colbase + col16];
    sc = g[colbase + col16] / sqrtf(fmaxf(t, 1e-12f));
  }
  for (int c = c0; c < c0 + cper; ++c) {
    for (int h = 0; h < 2; ++h) {
      int kk2 = kk + h * 16;
      int k = kbase + c * 32 + kk2;
      float v = src[(size_t)k * N + colbase + col16] * sc;
      int l = col16 | (((kk2 >> 3) & 3) << 4);
      tile[l * 8 + (kk2 & 7)] = f2bf(v);
    }
    __syncthreads();
    if (tid < 64)
      ((s16x8*)(dst + dstbase + (size_t)(c - c0) * 512))[tid] = ((s16x8*)tile)[tid];
    __syncthreads();
  }
}

// ---------------- embed X and pack x_t [32][64] into A-fragment order per t ----------
__global__ void xepack_k(const int* __restrict__ X, const float* __restrict__ embd,
                         unsigned short* __restrict__ xe) {
  int t = blockIdx.x;
  int tid = threadIdx.x;
  int l = tid & 63, tile = (tid >> 6) & 1, c2 = tid >> 7;
  int b = tile * 16 + (l & 15);
  int row = X[b * NTIME + t];
  int k0 = 32 * c2 + 8 * (l >> 4);
  size_t off = (size_t)t * 2048 + c2 * 1024 + tile * 512 + l * 8;
  for (int j = 0; j < 8; ++j) xe[off + j] = f2bf(embd[row * NEMBD + k0 + j]);
}

// ---------------- init states + barrier ---------------------------------------------
__global__ void init_k(const float* __restrict__ S, float* __restrict__ cst,
                       float* __restrict__ hst, unsigned short* __restrict__ hpk,
                       unsigned int* __restrict__ bar) {
  int e = blockIdx.x * 256 + threadIdx.x;
  if (e < NBATCH * HID) {
    float c = S[e], h = S[NBATCH * HID + e];
    cst[e] = c; hst[e] = h;
    int b = e >> 12, j = e & 4095;
    hpk[apoff(b, j)] = f2bf(h);
  }
  if (blockIdx.x == 0 && threadIdx.x < 512) bar[threadIdx.x] = 0u;
}

// ---------------- grid barrier: monotone generation, ACQUIRE spin --------------------
// bar[0] = arrival counter, bar[64] = published generation (separate cache line).
// Target generation is computed locally by every block -> no racy entry read.
__device__ __forceinline__ void gridbar(unsigned int* bar, unsigned gen) {
  __syncthreads();
  if (threadIdx.x == 0) {
    __threadfence();  // cheap: L2 kept clean by write-through stores
    unsigned a = __hip_atomic_fetch_add(&bar[0], 1u, __ATOMIC_ACQ_REL,
                                        __HIP_MEMORY_SCOPE_AGENT);
    if (a == 255u) {
      __hip_atomic_store(&bar[0], 0u, __ATOMIC_RELAXED, __HIP_MEMORY_SCOPE_AGENT);
      __hip_atomic_store(&bar[64], gen, __ATOMIC_RELEASE, __HIP_MEMORY_SCOPE_AGENT);
    } else {
      while (__hip_atomic_load(&bar[64], __ATOMIC_ACQUIRE, __HIP_MEMORY_SCOPE_AGENT) < gen)
        __builtin_amdgcn_s_sleep(2);
    }
  }
  __syncthreads();
}

#define MFMA(a, b, c) __builtin_amdgcn_mfma_f32_16x16x32_bf16(a, b, c, 0, 0, 0)
#define STORE_U32(p, v) __hip_atomic_store((p), (v), __ATOMIC_RELAXED, __HIP_MEMORY_SCOPE_AGENT)
#define STORE_U64(p, v) __hip_atomic_store((p), (v), __ATOMIC_RELAXED, __HIP_MEMORY_SCOPE_AGENT)

// ---------------- persistent recurrence: 64 steps, 2 grid barriers per step ----------
__global__ __launch_bounds__(1024, 4)
void rec_k(const unsigned short* __restrict__ whp, const unsigned short* __restrict__ wmhp,
           const unsigned short* __restrict__ wxp, const unsigned short* __restrict__ wmxp,
           const unsigned short* __restrict__ xe, const float* __restrict__ bias,
           const float* __restrict__ Mm, unsigned short* __restrict__ mpk,
           unsigned short* __restrict__ hpk, float* __restrict__ cst,
           float* __restrict__ hst, unsigned short* __restrict__ hflat,
           float* __restrict__ out, unsigned int* __restrict__ bar) {
  const int g = blockIdx.x;
  const int tid = threadIdx.x;
  const int w = tid >> 6, l = tid & 63;
  const int lo = l & 15, hi = l >> 4;
  const int gate = w & 3, ks = w >> 2;

  __shared__ float part[16][32][16];
  __shared__ float xmS[32][16];

  const s16x8* wmh_g = (const s16x8*)(wmhp + (size_t)g * 128 * 512);
  const s16x8* wh_w  = (const s16x8*)(whp  + (size_t)(g * 4 + gate) * 128 * 512);
  const s16x8* wx_w  = (const s16x8*)(wxp  + (size_t)(g * 4 + gate) * 2 * 512);
  const s16x8* wmx_g = (const s16x8*)(wmxp + (size_t)g * 2 * 512);

  // epilogue constants: 256 threads x 2 cols
  const int eb = tid >> 3, c0 = (tid & 7) * 2;
  const int ej = g * 16 + c0;
  float bI0 = 0.f, bI1 = 0.f, bF0 = 0.f, bF1 = 0.f, bO0 = 0.f, bO1 = 0.f, bU0 = 0.f, bU1 = 0.f;
  if (tid < 256) {
    bI0 = bias[ej];          bI1 = bias[ej + 1];
    bF0 = bias[4096 + ej];   bF1 = bias[4096 + ej + 1];
    bO0 = bias[8192 + ej];   bO1 = bias[8192 + ej + 1];
    bU0 = bias[12288 + ej];  bU1 = bias[12288 + ej + 1];
  }

  for (int t = 0; t < NTIME; ++t) {
    // ---- issue constant-weight loads early: phase-1 wmh slice + phase-2 wh batch 0
    s16x8 wmhr[8], wA[8], wB[8];
#pragma unroll
    for (int q = 0; q < 8; ++q) wmhr[q] = wmh_g[(w * 8 + q) * 64 + l];
#pragma unroll
    for (int q = 0; q < 8; ++q) wA[q] = wh_w[(ks * 32 + q) * 64 + l];

    // ---- phase 1: hm partials (K split 16 ways) ----
    f32x4 a0 = {0.f, 0.f, 0.f, 0.f}, a1 = {0.f, 0.f, 0.f, 0.f};
    {
      const s16x8* hp = (const s16x8*)hpk;
#pragma unroll
      for (int q = 0; q < 8; ++q) {
        int cc = w * 8 + q;
        a0 = MFMA(hp[cc * 128 + l], wmhr[q], a0);
        a1 = MFMA(hp[cc * 128 + 64 + l], wmhr[q], a1);
      }
    }
#pragma unroll
    for (int r = 0; r < 4; ++r) {
      part[w][4 * hi + r][lo] = a0[r];
      part[w][16 + 4 * hi + r][lo] = a1[r];
    }
    if (w == 0) {  // xm = x_t @ wmxn (K=64)
      f32x4 x0 = {0.f, 0.f, 0.f, 0.f}, x1 = {0.f, 0.f, 0.f, 0.f};
      const s16x8* xep = (const s16x8*)(xe + (size_t)t * 2048);
#pragma unroll
      for (int c2 = 0; c2 < 2; ++c2) {
        s16x8 bf = wmx_g[c2 * 64 + l];
        x0 = MFMA(xep[c2 * 128 + l], bf, x0);
        x1 = MFMA(xep[c2 * 128 + 64 + l], bf, x1);
      }
#pragma unroll
      for (int r = 0; r < 4; ++r) {
        xmS[4 * hi + r][lo] = x0[r];
        xmS[16 + 4 * hi + r][lo] = x1[r];
      }
    }
    __syncthreads();
    if (tid < 256) {
      float hm0 = 0.f, hm1 = 0.f;
#pragma unroll
      for (int k = 0; k < 16; ++k) {
        hm0 += part[k][eb][c0];
        hm1 += part[k][eb][c0 + 1];
      }
      unsigned pk = (unsigned)f2bf(xmS[eb][c0] * hm0) |
                    ((unsigned)f2bf(xmS[eb][c0 + 1] * hm1) << 16);
      STORE_U32((unsigned*)mpk + (apoff(eb, ej) >> 1), pk);
    }
    gridbar(bar, 2 * t + 1);

    // ---- phase 2: z partials, wh streamed via 8-chunk double buffer ----
    f32x4 z0 = {0.f, 0.f, 0.f, 0.f}, z1 = {0.f, 0.f, 0.f, 0.f};
    {
      const s16x8* mp = (const s16x8*)mpk;
#pragma unroll
      for (int q = 0; q < 8; ++q) wB[q] = wh_w[(ks * 32 + 8 + q) * 64 + l];
#pragma unroll
      for (int q = 0; q < 8; ++q) {
        int cc = ks * 32 + q;
        z0 = MFMA(mp[cc * 128 + l], wA[q], z0);
        z1 = MFMA(mp[cc * 128 + 64 + l], wA[q], z1);
      }
#pragma unroll
      for (int q = 0; q < 8; ++q) wA[q] = wh_w[(ks * 32 + 16 + q) * 64 + l];
#pragma unroll
      for (int q = 0; q < 8; ++q) {
        int cc = ks * 32 + 8 + q;
        z0 = MFMA(mp[cc * 128 + l], wB[q], z0);
        z1 = MFMA(mp[cc * 128 + 64 + l], wB[q], z1);
      }
#pragma unroll
      for (int q = 0; q < 8; ++q) wB[q] = wh_w[(ks * 32 + 24 + q) * 64 + l];
#pragma unroll
      for (int q = 0; q < 8; ++q) {
        int cc = ks * 32 + 16 + q;
        z0 = MFMA(mp[cc * 128 + l], wA[q], z0);
        z1 = MFMA(mp[cc * 128 + 64 + l], wA[q], z1);
      }
#pragma unroll
      for (int q = 0; q < 8; ++q) {
        int cc = ks * 32 + 24 + q;
        z0 = MFMA(mp[cc * 128 + l], wB[q], z0);
        z1 = MFMA(mp[cc * 128 + 64 + l], wB[q], z1);
      }
      if (ks == 0) {  // x @ wxn contribution (K=64)
        const s16x8* xep = (const s16x8*)(xe + (size_t)t * 2048);
#pragma unroll
        for (int c2 = 0; c2 < 2; ++c2) {
          s16x8 bf = wx_w[c2 * 64 + l];
          z0 = MFMA(xep[c2 * 128 + l], bf, z0);
          z1 = MFMA(xep[c2 * 128 + 64 + l], bf, z1);
        }
      }
    }
#pragma unroll
    for (int r = 0; r < 4; ++r) {
      part[w][4 * hi + r][lo] = z0[r];
      part[w][16 + 4 * hi + r][lo] = z1[r];
    }
    __syncthreads();
    if (tid < 256) {
      float iv0 = part[0][eb][c0] + part[4][eb][c0] + part[8][eb][c0] + part[12][eb][c0] + bI0;
      float iv1 = part[0][eb][c0+1] + part[4][eb][c0+1] + part[8][eb][c0+1] + part[12][eb][c0+1] + bI1;
      float fv0 = part[1][eb][c0] + part[5][eb][c0] + part[9][eb][c0] + part[13][eb][c0] + bF0;
      float fv1 = part[1][eb][c0+1] + part[5][eb][c0+1] + part[9][eb][c0+1] + part[13][eb][c0+1] + bF1;
      float ov0 = part[2][eb][c0] + part[6][eb][c0] + part[10][eb][c0] + part[14][eb][c0] + bO0;
      float ov1 = part[2][eb][c0+1] + part[6][eb][c0+1] + part[10][eb][c0+1] + part[14][eb][c0+1] + bO1;
      float uv0 = part[3][eb][c0] + part[7][eb][c0] + part[11][eb][c0] + part[15][eb][c0] + bU0;
      float uv1 = part[3][eb][c0+1] + part[7][eb][c0+1] + part[11][eb][c0+1] + part[15][eb][c0+1] + bU1;
      iv0 = 1.f / (1.f + __expf(-iv0)); iv1 = 1.f / (1.f + __expf(-iv1));
      fv0 = 1.f / (1.f + __expf(-fv0)); fv1 = 1.f / (1.f + __expf(-fv1));
      ov0 = 1.f / (1.f + __expf(-ov0)); ov1 = 1.f / (1.f + __expf(-ov1));
      uv0 = tanhf(uv0); uv1 = tanhf(uv1);
      size_t sj = (size_t)eb * HID + ej;
      float cp0 = cst[sj], cp1 = cst[sj + 1];
      float hp0 = hst[sj], hp1 = hst[sj + 1];
      float ct0 = fv0 * cp0 + iv0 * uv0, ct1 = fv1 * cp1 + iv1 * uv1;
      float ht0 = ov0 * tanhf(ct0), ht1 = ov1 * tanhf(ct1);
      float mt = Mm[eb * NTIME + t];
      float cn0 = ct0 * mt + cp0 * (1.f - mt), cn1 = ct1 * mt + cp1 * (1.f - mt);
      float hn0 = ht0 * mt + hp0 * (1.f - mt), hn1 = ht1 * mt + hp1 * (1.f - mt);
      STORE_U64((unsigned long long*)(cst + sj), pk2f(cn0, cn1));
      STORE_U64((unsigned long long*)(hst + sj), pk2f(hn0, hn1));
      STORE_U64((unsigned long long*)(out + ((size_t)t * NBATCH + eb) * HID + ej), pk2f(cn0, cn1));
      unsigned hpack = (unsigned)f2bf(hn0) | ((unsigned)f2bf(hn1) << 16);
      STORE_U32((unsigned*)hflat + ((((size_t)eb * NTIME + t) * HID + ej) >> 1), hpack);
      STORE_U32((unsigned*)hpk + (apoff(eb, ej) >> 1), hpack);
      if (t == NTIME - 1) {
        STORE_U64((unsigned long long*)(out + (size_t)NTIME * NBATCH * HID + sj), pk2f(cn0, cn1));
        STORE_U64((unsigned long long*)(out + (size_t)NTIME * NBATCH * HID + NBATCH * HID + sj),
                  pk2f(hn0, hn1));
      }
    }
    gridbar(bar, 2 * t + 2);
  }
}

// ---------------- logits = hflat @ w_out + b_out  ([2048,4096]x[4096,256]) -----------
__global__ __launch_bounds__(256)
void logits_k(const unsigned short* __restrict__ hflat,
              const unsigned short* __restrict__ woutp,
              const float* __restrict__ bout, float* __restrict__ out) {
  int r0 = blockIdx.x * 16;
  int tid = threadIdx.x, w = tid >> 6, l = tid & 63;
  int lo = l & 15, hi = l >> 4;
  f32x4 acc[4] = {{0.f,0.f,0.f,0.f},{0.f,0.f,0.f,0.f},{0.f,0.f,0.f,0.f},{0.f,0.f,0.f,0.f}};
  const unsigned short* arow = hflat + (size_t)(r0 + lo) * HID;
  const s16x8* wp = (const s16x8*)woutp;
#pragma unroll 2
  for (int c = 0; c < 128; ++c) {
    s16x8 af = *(const s16x8*)(arow + c * 32 + 8 * hi);
#pragma unroll
    for (int q = 0; q < 4; ++q) {
      int nt = w * 4 + q;
      acc[q] = MFMA(af, wp[(nt * 128 + c) * 64 + l], acc[q]);
    }
  }
#pragma unroll
  for (int q = 0; q < 4; ++q) {
    int nt = w * 4 + q;
    int col = nt * 16 + lo;
    float bo = bout[col];
#pragma unroll
    for (int r = 0; r < 4; ++r)
      out[(size_t)(r0 + 4 * hi + r) * NVOCAB + col] = acc[q][r] + bo;
  }
}

extern "C" void kernel_launch(void* const* d_in, const int* in_sizes, int n_in,
                              void* d_out, int out_size, void* d_ws, size_t ws_size,
                              hipStream_t stream) {
  const int*   X    = (const int*)d_in[0];
  const float* Mm   = (const float*)d_in[1];
  const float* S    = (const float*)d_in[2];
  const float* embd = (const float*)d_in[3];
  const float* wx   = (const float*)d_in[4];
  const float* wh   = (const float*)d_in[5];
  const float* wmx  = (const float*)d_in[6];
  const float* wmh  = (const float*)d_in[7];
  const float* b    = (const float*)d_in[8];
  const float* gx   = (const float*)d_in[9];
  const float* gh   = (const float*)d_in[10];
  const float* gmx  = (const float*)d_in[11];
  const float* gmh  = (const float*)d_in[12];
  const float* wout = (const float*)d_in[13];
  const float* bout = (const float*)d_in[14];
  float* out = (float*)d_out;
  char* ws = (char*)d_ws;

  size_t cur = 0;
  auto alloc = [&](size_t bytes) { size_t o = cur; cur += (bytes + 255) & ~size_t(255); return o; };
  unsigned short* WHP   = (unsigned short*)(ws + alloc((size_t)1024 * 128 * 512 * 2)); // 128MB
  unsigned short* WMHP  = (unsigned short*)(ws + alloc((size_t)1024 * 32 * 512 * 2));  // 32MB
  unsigned short* WXP   = (unsigned short*)(ws + alloc((size_t)1024 * 2 * 512 * 2));   // 2MB
  unsigned short* WMXP  = (unsigned short*)(ws + alloc((size_t)256 * 2 * 512 * 2));    // 0.5MB
  unsigned short* WOUTP = (unsigned short*)(ws + alloc((size_t)16 * 128 * 512 * 2));   // 2MB
  unsigned short* XE    = (unsigned short*)(ws + alloc((size_t)64 * 2048 * 2));        // 256KB
  unsigned short* MPK   = (unsigned short*)(ws + alloc((size_t)32 * 4096 * 2));        // 256KB
  unsigned short* HPK   = (unsigned short*)(ws + alloc((size_t)32 * 4096 * 2));        // 256KB
  float* CST            = (float*)(ws + alloc((size_t)32 * 4096 * 4));
  float* HST            = (float*)(ws + alloc((size_t)32 * 4096 * 4));
  unsigned short* HFLAT = (unsigned short*)(ws + alloc((size_t)2048 * 4096 * 2));      // 16MB
  float* SSH            = (float*)(ws + alloc((size_t)8 * 16384 * 4));
  float* SSMH           = (float*)(ws + alloc((size_t)8 * 4096 * 4));
  float* SSX            = (float*)(ws + alloc((size_t)16384 * 4));
  float* SSMX           = (float*)(ws + alloc((size_t)4096 * 4));
  unsigned int* BAR     = (unsigned int*)(ws + alloc(2048));
  (void)ws_size; (void)in_sizes; (void)n_in; (void)out_size;

  // stage-1 column sums of squares (parallel, deterministic)
  colsum_k<<<dim3(256, 8), 256, 0, stream>>>(wh,  SSH,  HID, G4,  8);
  colsum_k<<<dim3(64, 8),  256, 0, stream>>>(wmh, SSMH, HID, HID, 8);
  colsum_k<<<dim3(256, 1), 256, 0, stream>>>(wx,  SSX,  NEMBD, G4,  1);
  colsum_k<<<dim3(64, 1),  256, 0, stream>>>(wmx, SSMX, NEMBD, HID, 1);

  // pack weights into bf16 fragment order (scale finalized in-kernel)
  pack_k<<<dim3(1024, 8), 256, 0, stream>>>(wh,  SSH,  gh,  WHP,  G4,  4096, 2, 0,    128, 8);
  pack_k<<<dim3(1024, 4), 256, 0, stream>>>(wmh, SSMH, gmh, WMHP, HID, 0,    2, 1024, 32,  8);
  pack_k<<<dim3(1024, 1), 256, 0, stream>>>(wx,  SSX,  gx,  WXP,  G4,  4096, 2, 0,    2,   1);
  pack_k<<<dim3(256, 1),  256, 0, stream>>>(wmx, SSMX, gmx, WMXP, HID, 0,    0, 0,    2,   1);
  pack_k<<<dim3(16, 1),   256, 0, stream>>>(wout, nullptr, nullptr, WOUTP, NVOCAB, 0, 0, 0, 128, 0);

  xepack_k<<<64, 256, 0, stream>>>(X, embd, XE);
  init_k<<<512, 256, 0, stream>>>(S, CST, HST, HPK, BAR);

  rec_k<<<256, 1024, 0, stream>>>(WHP, WMHP, WXP, WMXP, XE, b, Mm, MPK, HPK, CST, HST,
                                  HFLAT, out, BAR);

  logits_k<<<128, 256, 0, stream>>>(HFLAT, WOUTP, bout,
                                    out + (size_t)NTIME * NBATCH * HID + 2 * NBATCH * HID);
}

// Round 5
// 2827.111 us; speedup vs baseline: 3.2362x; 3.2362x over previous
//
#include <hip/hip_runtime.h>
#include <hip/hip_bf16.h>

#define HID 4096
#define NEMBD 64
#define NBATCH 32
#define NTIME 64
#define NVOCAB 256
#define G4 16384

typedef __attribute__((ext_vector_type(4))) float f32x4;
typedef __attribute__((ext_vector_type(8))) short s16x8;

__device__ __forceinline__ unsigned short f2bf(float f) {
  union { float f; unsigned u; } v; v.f = f;
  unsigned u = v.u + 0x7FFFu + ((v.u >> 16) & 1u);
  return (unsigned short)(u >> 16);
}

// A-fragment packed offset for a [32 rows][4096 k] bf16 matrix, chunked by 32k:
// chunk*1024 + tile512*(row>=16) + lane*8 + elem, lane = (row&15) | (((k>>3)&3)<<4)
__device__ __forceinline__ int apoff(int b, int j) {
  return ((j >> 5) << 10) | ((b >> 4) << 9) |
         (((b & 15) | (((j >> 3) & 3) << 4)) << 3) | (j & 7);
}

// ---------------- stage 1: partial column sums of squares (deterministic K-split) ----
__global__ void colsum_k(const float* __restrict__ w, float* __restrict__ ss,
                         int K, int N, int KS) {
  int col = threadIdx.x & 63, kg = threadIdx.x >> 6;
  int j = blockIdx.x * 64 + col;
  int kper = K / KS;
  int k0 = blockIdx.y * kper;
  float s = 0.f;
#pragma unroll 4
  for (int k = k0 + kg; k < k0 + kper; k += 4) {
    float v = w[(size_t)k * N + j];
    s += v * v;
  }
  __shared__ float red[4][64];
  red[kg][col] = s;
  __syncthreads();
  if (threadIdx.x < 64)
    ss[(size_t)blockIdx.y * N + j] = red[0][col] + red[1][col] + red[2][col] + red[3][col];
}

// ---------------- pack fp32 [K][N] column-slice into bf16 B-fragment order -----------
__global__ void pack_k(const float* __restrict__ src, const float* __restrict__ ss,
                       const float* __restrict__ g, unsigned short* __restrict__ dst,
                       int N, int Cw, int S, int Kw, int nch, int KS) {
  int bid = blockIdx.x;
  int colbase = (bid & 3) * Cw + (bid >> S) * 16;
  int kbase = (bid & 3) * Kw;
  int cper = nch / gridDim.y;
  int c0 = blockIdx.y * cper;
  size_t dstbase = (size_t)bid * nch * 512 + (size_t)c0 * 512;
  __shared__ unsigned short tile[512];
  int tid = threadIdx.x;
  int col16 = tid & 15, kk = tid >> 4;
  float sc = 1.f;
  if (ss) {
    float t = 0.f;
    for (int q = 0; q < KS; ++q) t += ss[(size_t)q * N + colbase + col16];
    sc = g[colbase + col16] / sqrtf(fmaxf(t, 1e-12f));
  }
  for (int c = c0; c < c0 + cper; ++c) {
    for (int h = 0; h < 2; ++h) {
      int kk2 = kk + h * 16;
      int k = kbase + c * 32 + kk2;
      float v = src[(size_t)k * N + colbase + col16] * sc;
      int l = col16 | (((kk2 >> 3) & 3) << 4);
      tile[l * 8 + (kk2 & 7)] = f2bf(v);
    }
    __syncthreads();
    if (tid < 64)
      ((s16x8*)(dst + dstbase + (size_t)(c - c0) * 512))[tid] = ((s16x8*)tile)[tid];
    __syncthreads();
  }
}

// ---------------- embed X and pack x_t [32][64] into A-fragment order per t ----------
__global__ void xepack_k(const int* __restrict__ X, const float* __restrict__ embd,
                         unsigned short* __restrict__ xe) {
  int t = blockIdx.x;
  int tid = threadIdx.x;
  int l = tid & 63, tile = (tid >> 6) & 1, c2 = tid >> 7;
  int b = tile * 16 + (l & 15);
  int row = X[b * NTIME + t];
  int k0 = 32 * c2 + 8 * (l >> 4);
  size_t off = (size_t)t * 2048 + c2 * 1024 + tile * 512 + l * 8;
  for (int j = 0; j < 8; ++j) xe[off + j] = f2bf(embd[row * NEMBD + k0 + j]);
}

// ---------------- init states -------------------------------------------------------
__global__ void init_k(const float* __restrict__ S, float* __restrict__ cst,
                       float* __restrict__ hst, unsigned short* __restrict__ hpk) {
  int e = blockIdx.x * 256 + threadIdx.x;
  if (e < NBATCH * HID) {
    float c = S[e], h = S[NBATCH * HID + e];
    cst[e] = c; hst[e] = h;
    int b = e >> 12, j = e & 4095;
    hpk[apoff(b, j)] = f2bf(h);
  }
}

#define MFMA(a, b, c) __builtin_amdgcn_mfma_f32_16x16x32_bf16(a, b, c, 0, 0, 0)

// ---------------- phase 1 of step t: hm = h@wmhn (K split 16 ways), m = xm*hm --------
__global__ __launch_bounds__(1024)
void ph1_k(const unsigned short* __restrict__ wmhp, const unsigned short* __restrict__ wmxp,
           const unsigned short* __restrict__ xe, const unsigned short* __restrict__ hpk,
           unsigned short* __restrict__ mpk, int t) {
  const int g = blockIdx.x;
  const int tid = threadIdx.x;
  const int w = tid >> 6, l = tid & 63;
  const int lo = l & 15, hi = l >> 4;

  __shared__ float part[16][32][16];
  __shared__ float xmS[32][16];

  const s16x8* wmh_g = (const s16x8*)(wmhp + (size_t)g * 128 * 512);
  const s16x8* wmx_g = (const s16x8*)(wmxp + (size_t)g * 2 * 512);
  const s16x8* hp = (const s16x8*)hpk;

  f32x4 a0 = {0.f, 0.f, 0.f, 0.f}, a1 = {0.f, 0.f, 0.f, 0.f};
#pragma unroll
  for (int q = 0; q < 8; ++q) {
    int cc = w * 8 + q;
    s16x8 bf = wmh_g[cc * 64 + l];
    a0 = MFMA(hp[cc * 128 + l], bf, a0);
    a1 = MFMA(hp[cc * 128 + 64 + l], bf, a1);
  }
#pragma unroll
  for (int r = 0; r < 4; ++r) {
    part[w][4 * hi + r][lo] = a0[r];
    part[w][16 + 4 * hi + r][lo] = a1[r];
  }
  if (w == 0) {  // xm = x_t @ wmxn (K=64)
    f32x4 x0 = {0.f, 0.f, 0.f, 0.f}, x1 = {0.f, 0.f, 0.f, 0.f};
    const s16x8* xep = (const s16x8*)(xe + (size_t)t * 2048);
#pragma unroll
    for (int c2 = 0; c2 < 2; ++c2) {
      s16x8 bf = wmx_g[c2 * 64 + l];
      x0 = MFMA(xep[c2 * 128 + l], bf, x0);
      x1 = MFMA(xep[c2 * 128 + 64 + l], bf, x1);
    }
#pragma unroll
    for (int r = 0; r < 4; ++r) {
      xmS[4 * hi + r][lo] = x0[r];
      xmS[16 + 4 * hi + r][lo] = x1[r];
    }
  }
  __syncthreads();
  if (tid < 256) {
    const int eb = tid >> 3, c0 = (tid & 7) * 2;
    const int ej = g * 16 + c0;
    float hm0 = 0.f, hm1 = 0.f;
#pragma unroll
    for (int k = 0; k < 16; ++k) {
      hm0 += part[k][eb][c0];
      hm1 += part[k][eb][c0 + 1];
    }
    unsigned pk = (unsigned)f2bf(xmS[eb][c0] * hm0) |
                  ((unsigned)f2bf(xmS[eb][c0 + 1] * hm1) << 16);
    ((unsigned*)mpk)[apoff(eb, ej) >> 1] = pk;
  }
}

// ---------------- phase 2 of step t: z = x@wxn + m@whn + b ; gates ; update ----------
__global__ __launch_bounds__(1024)
void ph2_k(const unsigned short* __restrict__ whp, const unsigned short* __restrict__ wxp,
           const unsigned short* __restrict__ xe, const float* __restrict__ bias,
           const float* __restrict__ Mm, const unsigned short* __restrict__ mpk,
           unsigned short* __restrict__ hpk, float* __restrict__ cst,
           float* __restrict__ hst, unsigned short* __restrict__ hflat,
           float* __restrict__ out, int t) {
  const int g = blockIdx.x;
  const int tid = threadIdx.x;
  const int w = tid >> 6, l = tid & 63;
  const int lo = l & 15, hi = l >> 4;
  const int gate = w & 3, ks = w >> 2;

  __shared__ float part[16][32][16];

  const s16x8* wh_w = (const s16x8*)(whp + (size_t)(g * 4 + gate) * 128 * 512);
  const s16x8* wx_w = (const s16x8*)(wxp + (size_t)(g * 4 + gate) * 2 * 512);
  const s16x8* mp = (const s16x8*)mpk;

  f32x4 z0 = {0.f, 0.f, 0.f, 0.f}, z1 = {0.f, 0.f, 0.f, 0.f};
#pragma unroll 4
  for (int q = 0; q < 32; ++q) {
    int cc = ks * 32 + q;
    s16x8 bf = wh_w[cc * 64 + l];
    z0 = MFMA(mp[cc * 128 + l], bf, z0);
    z1 = MFMA(mp[cc * 128 + 64 + l], bf, z1);
  }
  if (ks == 0) {  // x @ wxn contribution (K=64)
    const s16x8* xep = (const s16x8*)(xe + (size_t)t * 2048);
#pragma unroll
    for (int c2 = 0; c2 < 2; ++c2) {
      s16x8 bf = wx_w[c2 * 64 + l];
      z0 = MFMA(xep[c2 * 128 + l], bf, z0);
      z1 = MFMA(xep[c2 * 128 + 64 + l], bf, z1);
    }
  }
#pragma unroll
  for (int r = 0; r < 4; ++r) {
    part[w][4 * hi + r][lo] = z0[r];
    part[w][16 + 4 * hi + r][lo] = z1[r];
  }
  __syncthreads();
  if (tid < 256) {
    const int eb = tid >> 3, c0 = (tid & 7) * 2;
    const int ej = g * 16 + c0;
    float iv0 = part[0][eb][c0] + part[4][eb][c0] + part[8][eb][c0] + part[12][eb][c0] + bias[ej];
    float iv1 = part[0][eb][c0+1] + part[4][eb][c0+1] + part[8][eb][c0+1] + part[12][eb][c0+1] + bias[ej + 1];
    float fv0 = part[1][eb][c0] + part[5][eb][c0] + part[9][eb][c0] + part[13][eb][c0] + bias[4096 + ej];
    float fv1 = part[1][eb][c0+1] + part[5][eb][c0+1] + part[9][eb][c0+1] + part[13][eb][c0+1] + bias[4096 + ej + 1];
    float ov0 = part[2][eb][c0] + part[6][eb][c0] + part[10][eb][c0] + part[14][eb][c0] + bias[8192 + ej];
    float ov1 = part[2][eb][c0+1] + part[6][eb][c0+1] + part[10][eb][c0+1] + part[14][eb][c0+1] + bias[8192 + ej + 1];
    float uv0 = part[3][eb][c0] + part[7][eb][c0] + part[11][eb][c0] + part[15][eb][c0] + bias[12288 + ej];
    float uv1 = part[3][eb][c0+1] + part[7][eb][c0+1] + part[11][eb][c0+1] + part[15][eb][c0+1] + bias[12288 + ej + 1];
    iv0 = 1.f / (1.f + __expf(-iv0)); iv1 = 1.f / (1.f + __expf(-iv1));
    fv0 = 1.f / (1.f + __expf(-fv0)); fv1 = 1.f / (1.f + __expf(-fv1));
    ov0 = 1.f / (1.f + __expf(-ov0)); ov1 = 1.f / (1.f + __expf(-ov1));
    uv0 = tanhf(uv0); uv1 = tanhf(uv1);
    size_t sj = (size_t)eb * HID + ej;
    float cp0 = cst[sj], cp1 = cst[sj + 1];
    float hp0 = hst[sj], hp1 = hst[sj + 1];
    float ct0 = fv0 * cp0 + iv0 * uv0, ct1 = fv1 * cp1 + iv1 * uv1;
    float ht0 = ov0 * tanhf(ct0), ht1 = ov1 * tanhf(ct1);
    float mt = Mm[eb * NTIME + t];
    float cn0 = ct0 * mt + cp0 * (1.f - mt), cn1 = ct1 * mt + cp1 * (1.f - mt);
    float hn0 = ht0 * mt + hp0 * (1.f - mt), hn1 = ht1 * mt + hp1 * (1.f - mt);
    cst[sj] = cn0; cst[sj + 1] = cn1;
    hst[sj] = hn0; hst[sj + 1] = hn1;
    out[((size_t)t * NBATCH + eb) * HID + ej] = cn0;
    out[((size_t)t * NBATCH + eb) * HID + ej + 1] = cn1;
    unsigned hpack = (unsigned)f2bf(hn0) | ((unsigned)f2bf(hn1) << 16);
    ((unsigned*)hflat)[(((size_t)eb * NTIME + t) * HID + ej) >> 1] = hpack;
    ((unsigned*)hpk)[apoff(eb, ej) >> 1] = hpack;
    if (t == NTIME - 1) {
      out[(size_t)NTIME * NBATCH * HID + sj] = cn0;
      out[(size_t)NTIME * NBATCH * HID + sj + 1] = cn1;
      out[(size_t)NTIME * NBATCH * HID + NBATCH * HID + sj] = hn0;
      out[(size_t)NTIME * NBATCH * HID + NBATCH * HID + sj + 1] = hn1;
    }
  }
}

// ---------------- logits = hflat @ w_out + b_out  ([2048,4096]x[4096,256]) -----------
__global__ __launch_bounds__(256)
void logits_k(const unsigned short* __restrict__ hflat,
              const unsigned short* __restrict__ woutp,
              const float* __restrict__ bout, float* __restrict__ out) {
  int r0 = blockIdx.x * 16;
  int tid = threadIdx.x, w = tid >> 6, l = tid & 63;
  int lo = l & 15, hi = l >> 4;
  f32x4 acc[4] = {{0.f,0.f,0.f,0.f},{0.f,0.f,0.f,0.f},{0.f,0.f,0.f,0.f},{0.f,0.f,0.f,0.f}};
  const unsigned short* arow = hflat + (size_t)(r0 + lo) * HID;
  const s16x8* wp = (const s16x8*)woutp;
#pragma unroll 2
  for (int c = 0; c < 128; ++c) {
    s16x8 af = *(const s16x8*)(arow + c * 32 + 8 * hi);
#pragma unroll
    for (int q = 0; q < 4; ++q) {
      int nt = w * 4 + q;
      acc[q] = MFMA(af, wp[(nt * 128 + c) * 64 + l], acc[q]);
    }
  }
#pragma unroll
  for (int q = 0; q < 4; ++q) {
    int nt = w * 4 + q;
    int col = nt * 16 + lo;
    float bo = bout[col];
#pragma unroll
    for (int r = 0; r < 4; ++r)
      out[(size_t)(r0 + 4 * hi + r) * NVOCAB + col] = acc[q][r] + bo;
  }
}

extern "C" void kernel_launch(void* const* d_in, const int* in_sizes, int n_in,
                              void* d_out, int out_size, void* d_ws, size_t ws_size,
                              hipStream_t stream) {
  const int*   X    = (const int*)d_in[0];
  const float* Mm   = (const float*)d_in[1];
  const float* S    = (const float*)d_in[2];
  const float* embd = (const float*)d_in[3];
  const float* wx   = (const float*)d_in[4];
  const float* wh   = (const float*)d_in[5];
  const float* wmx  = (const float*)d_in[6];
  const float* wmh  = (const float*)d_in[7];
  const float* b    = (const float*)d_in[8];
  const float* gx   = (const float*)d_in[9];
  const float* gh   = (const float*)d_in[10];
  const float* gmx  = (const float*)d_in[11];
  const float* gmh  = (const float*)d_in[12];
  const float* wout = (const float*)d_in[13];
  const float* bout = (const float*)d_in[14];
  float* out = (float*)d_out;
  char* ws = (char*)d_ws;

  size_t cur = 0;
  auto alloc = [&](size_t bytes) { size_t o = cur; cur += (bytes + 255) & ~size_t(255); return o; };
  unsigned short* WHP   = (unsigned short*)(ws + alloc((size_t)1024 * 128 * 512 * 2)); // 128MB
  unsigned short* WMHP  = (unsigned short*)(ws + alloc((size_t)1024 * 32 * 512 * 2));  // 32MB
  unsigned short* WXP   = (unsigned short*)(ws + alloc((size_t)1024 * 2 * 512 * 2));   // 2MB
  unsigned short* WMXP  = (unsigned short*)(ws + alloc((size_t)256 * 2 * 512 * 2));    // 0.5MB
  unsigned short* WOUTP = (unsigned short*)(ws + alloc((size_t)16 * 128 * 512 * 2));   // 2MB
  unsigned short* XE    = (unsigned short*)(ws + alloc((size_t)64 * 2048 * 2));        // 256KB
  unsigned short* MPK   = (unsigned short*)(ws + alloc((size_t)32 * 4096 * 2));        // 256KB
  unsigned short* HPK   = (unsigned short*)(ws + alloc((size_t)32 * 4096 * 2));        // 256KB
  float* CST            = (float*)(ws + alloc((size_t)32 * 4096 * 4));
  float* HST            = (float*)(ws + alloc((size_t)32 * 4096 * 4));
  unsigned short* HFLAT = (unsigned short*)(ws + alloc((size_t)2048 * 4096 * 2));      // 16MB
  float* SSH            = (float*)(ws + alloc((size_t)8 * 16384 * 4));
  float* SSMH           = (float*)(ws + alloc((size_t)8 * 4096 * 4));
  float* SSX            = (float*)(ws + alloc((size_t)16384 * 4));
  float* SSMX           = (float*)(ws + alloc((size_t)4096 * 4));
  (void)ws_size; (void)in_sizes; (void)n_in; (void)out_size;

  // stage-1 column sums of squares (parallel, deterministic)
  colsum_k<<<dim3(256, 8), 256, 0, stream>>>(wh,  SSH,  HID, G4,  8);
  colsum_k<<<dim3(64, 8),  256, 0, stream>>>(wmh, SSMH, HID, HID, 8);
  colsum_k<<<dim3(256, 1), 256, 0, stream>>>(wx,  SSX,  NEMBD, G4,  1);
  colsum_k<<<dim3(64, 1),  256, 0, stream>>>(wmx, SSMX, NEMBD, HID, 1);

  // pack weights into bf16 fragment order (scale finalized in-kernel)
  pack_k<<<dim3(1024, 8), 256, 0, stream>>>(wh,  SSH,  gh,  WHP,  G4,  4096, 2, 0,    128, 8);
  pack_k<<<dim3(1024, 4), 256, 0, stream>>>(wmh, SSMH, gmh, WMHP, HID, 0,    2, 1024, 32,  8);
  pack_k<<<dim3(1024, 1), 256, 0, stream>>>(wx,  SSX,  gx,  WXP,  G4,  4096, 2, 0,    2,   1);
  pack_k<<<dim3(256, 1),  256, 0, stream>>>(wmx, SSMX, gmx, WMXP, HID, 0,    0, 0,    2,   1);
  pack_k<<<dim3(16, 1),   256, 0, stream>>>(wout, nullptr, nullptr, WOUTP, NVOCAB, 0, 0, 0, 128, 0);

  xepack_k<<<64, 256, 0, stream>>>(X, embd, XE);
  init_k<<<512, 256, 0, stream>>>(S, CST, HST, HPK);

  // 64 steps, 2 kernels per step — stream ordering replaces the grid barrier
  for (int t = 0; t < NTIME; ++t) {
    ph1_k<<<256, 1024, 0, stream>>>(WMHP, WMXP, XE, HPK, MPK, t);
    ph2_k<<<256, 1024, 0, stream>>>(WHP, WXP, XE, b, Mm, MPK, HPK, CST, HST, HFLAT, out, t);
  }

  logits_k<<<128, 256, 0, stream>>>(HFLAT, WOUTP, bout,
                                    out + (size_t)NTIME * NBATCH * HID + 2 * NBATCH * HID);
}